// Round 12
// baseline (204.977 us; speedup 1.0000x reference)
//
#include <hip/hip_runtime.h>

#define WS 128
#define HW (1024 * 1024)
#define PLANE 8388608   // C * WS * WS = 512 * 16384

typedef _Float16 half4 __attribute__((ext_vector_type(4)));
typedef _Float16 half8 __attribute__((ext_vector_type(8)));
typedef float floatx4 __attribute__((ext_vector_type(4)));

// Kernel A: G[px][e] = fp16(xs[e][px]) for e<7, 0 pad at e=7.  16 B/px.
__global__ __launch_bounds__(256) void precompute_G(
    const float* __restrict__ x,      // (6, 1024, 1024)
    const float* __restrict__ sigma,  // (1, 1024, 1024)
    _Float16* __restrict__ G)         // (1024*1024, 8)
{
    const int px = blockIdx.x * 256 + threadIdx.x;
    half8 g;
#pragma unroll
    for (int e = 0; e < 6; ++e) g[e] = (_Float16)x[e * HW + px];
    g[6] = (_Float16)sigma[px];
    g[7] = (_Float16)0.0f;
    *(half8*)(G + (size_t)px * 8) = g;
}

// Kernel B: EXACT R7 arithmetic (best measured, 192.7; folds/NT/MFMA3 all
// reverted as regressions or nulls).  R12's single delta: FULL-DEPTH prefetch —
// the wave's entire 8-iteration fragment set (32 x 8B loads) is issued upfront
// into statically-indexed registers v[8][4] (full unroll, no runtime indexing,
// ZERO rotate movs — the R8 3-stage's per-iter rotation cost is gone).
// Rationale: prefetch depth is the only lever with confirmed positive slope
// (depth 1->2 = -8 us); R8's depth-3 regression was confounded with C-folds
// (R10 regressed with folds and no depth change).  +64 VGPR halves occupancy
// to ~16 waves/CU, but per-wave memory parallelism rises 8x -> net in-flight
// bytes/CU up 4x, which is what a latency-exposed loop needs.
__global__ __launch_bounds__(256) void instanseg_mlp(
    const _Float16* __restrict__ G,   // (1024*1024, 8)
    const float* __restrict__ c,      // (512, 6)
    const float* __restrict__ W1,     // (7, 16)
    const float* __restrict__ b1,     // (16)
    const float* __restrict__ W2,     // (16, 16)
    const float* __restrict__ b2,     // (16)
    const float* __restrict__ W3,     // (16, 1)
    const float* __restrict__ b3,     // (1)
    const int*   __restrict__ cent,   // (512, 2)
    float* __restrict__ out)
{
    const int cid  = blockIdx.y;
    const int lane = threadIdx.x & 63;
    const int wave = threadIdx.x >> 6;
    const int quad = lane >> 4;
    const int sub  = lane & 15;

    const int cy = min(max(cent[2 * cid], 64), 960);
    const int cx = min(max(cent[2 * cid + 1], 64), 960);
    const int cy0 = cy - 64, cx0 = cx - 64;

    // MFMA1 A-fragment: A[m=sub][k=4*quad+i] = W1[k][sub] (0 for k >= 7)
    half4 a1;
#pragma unroll
    for (int i = 0; i < 4; ++i) {
        const int k = 4 * quad + i;
        a1[i] = (k < 7) ? (_Float16)W1[k * 16 + sub] : (_Float16)0.0f;
    }

    // MFMA2 A-fragment + f32 layer-1 offset q and layer-2/3 constants
    half4 a2;
    float w3f[4], bb2[4], qf[4];
#pragma unroll
    for (int i = 0; i < 4; ++i) {
        const int k = 4 * quad + i;
        a2[i]  = (_Float16)W2[k * 16 + sub];
        w3f[i] = W3[k];
        bb2[i] = b2[k];
        float qv = -b1[k];
#pragma unroll
        for (int e = 0; e < 6; ++e)
            qv = fmaf(W1[e * 16 + k], c[cid * 6 + e], qv);
        qf[i] = qv;
    }
    const float b3v = b3[0];
    const floatx4 zero = {0.0f, 0.0f, 0.0f, 0.0f};

    const int wavestart = blockIdx.x * 2048 + wave * 512;

    // ---- full-depth upfront gather: all 8 iterations' fragments in flight.
    //      Quads 0-1 carry channels k=0..7; quads 2-3 must stay zero (MFMA1
    //      B-fragment rows k>=8).  v[it][ch] fully unrolled -> static regs. ----
    half4 v[8][4];
#pragma unroll
    for (int it = 0; it < 8; ++it) {
        const int s = wavestart + it * 64;
        // s is a multiple of 64; each iteration's 64 px are one contiguous
        // row segment: row cy0 + (s>>7), cols cx0 + (s&127) .. +64
        const int base = (cy0 + (s >> 7)) * 1024 + cx0 + (s & 127) + sub;
        const _Float16* rowp = G + (size_t)base * 8 + quad * 4;
        if (quad < 2) {
#pragma unroll
            for (int ch = 0; ch < 4; ++ch)
                v[it][ch] = *(const half4*)(rowp + ch * 128);   // 16 px * 8 ch
        } else {
#pragma unroll
            for (int ch = 0; ch < 4; ++ch)
                v[it][ch] = (half4)(_Float16)0.0f;
        }
    }

#pragma unroll
    for (int it = 0; it < 8; ++it) {
        const int start = wavestart + it * 64;

        float logit[4];
#pragma unroll
        for (int ch = 0; ch < 4; ++ch) {
            // layer 1 on the matrix pipe
            floatx4 c1 = __builtin_amdgcn_mfma_f32_16x16x16f16(a1, v[it][ch], zero, 0, 0, 0);

            // h = relu(c1 - q), single fp16 rounding — C-layout == B-layout
            half4 h;
#pragma unroll
            for (int i = 0; i < 4; ++i)
                h[i] = (_Float16)fmaxf(c1[i] - qf[i], 0.0f);

            // layer 2 on the matrix pipe
            floatx4 c2 = __builtin_amdgcn_mfma_f32_16x16x16f16(a2, h, zero, 0, 0, 0);

            float part = 0.0f;
#pragma unroll
            for (int i = 0; i < 4; ++i)
                part = fmaf(w3f[i], fmaxf(c2[i] + bb2[i], 0.0f), part);
            part += __shfl_xor(part, 16, 64);
            part += __shfl_xor(part, 32, 64);
            logit[ch] = part;
        }

        const float l01 = (quad & 1) ? logit[1] : logit[0];
        const float l23 = (quad & 1) ? logit[3] : logit[2];
        const float lg  = (quad & 2) ? l23 : l01;
        const float prob = 1.0f / (1.0f + __expf(-(lg + b3v)));

        const int rowy = cy0 + (start >> 7);            // wave-uniform
        const int colx = cx0 + (start & 127) + lane;
        const int n    = cid * 16384 + start + lane;
        out[n]             = prob;
        out[PLANE + n]     = (float)cid;
        out[2 * PLANE + n] = (float)rowy;
        out[3 * PLANE + n] = (float)colx;
    }
}

extern "C" void kernel_launch(void* const* d_in, const int* in_sizes, int n_in,
                              void* d_out, int out_size, void* d_ws, size_t ws_size,
                              hipStream_t stream) {
    const float* x     = (const float*)d_in[0];
    const float* sigma = (const float*)d_in[1];
    const float* c     = (const float*)d_in[2];
    const float* W1    = (const float*)d_in[3];
    const float* b1    = (const float*)d_in[4];
    const float* W2    = (const float*)d_in[5];
    const float* b2    = (const float*)d_in[6];
    const float* W3    = (const float*)d_in[7];
    const float* b3    = (const float*)d_in[8];
    const int*   cent  = (const int*)d_in[9];
    float* out = (float*)d_out;
    _Float16* G = (_Float16*)d_ws;   // 1024*1024*8 fp16 = 16 MB scratch

    precompute_G<<<dim3(HW / 256), dim3(256), 0, stream>>>(x, sigma, G);
    instanseg_mlp<<<dim3(8, 512), dim3(256), 0, stream>>>(
        G, c, W1, b1, W2, b2, W3, b3, cent, out);
}

// Round 13
// 194.857 us; speedup vs baseline: 1.0519x; 1.0519x over previous
//
#include <hip/hip_runtime.h>

#define WS 128
#define HW (1024 * 1024)
#define PLANE 8388608   // C * WS * WS = 512 * 16384

typedef _Float16 half4 __attribute__((ext_vector_type(4)));
typedef _Float16 half8 __attribute__((ext_vector_type(8)));
typedef float floatx4 __attribute__((ext_vector_type(4)));

// FINAL OPERATING POINT (restored R7, best of 13 measured variants: 192.7 us).
// Structure: A) precompute fp16-packed inputs G (16 B/px — the R5 byte-cut,
// -10 us); B) per-window MLP entirely on the matrix pipe with a 2-stage
// software-pipelined gather (depth 2 measured optimal: depth1=201, depth2=192.7,
// depth8=205).  Tested to null/regression: Morton/XCD placement x3, NT stores x2,
// MFMA C-operand folds x2, MFMA3 epilogue, 3-stage rotate, row/tile fusion.
// Budget: 125 us harness fills (fixed) + A 7.5 us (traffic floor) + B ~60 us
// (4.5 TB/s effective vs ~5-5.5 TB/s mixed gather+store ceiling).
__global__ __launch_bounds__(256) void precompute_G(
    const float* __restrict__ x,      // (6, 1024, 1024)
    const float* __restrict__ sigma,  // (1, 1024, 1024)
    _Float16* __restrict__ G)         // (1024*1024, 8)
{
    const int px = blockIdx.x * 256 + threadIdx.x;
    half8 g;
#pragma unroll
    for (int e = 0; e < 6; ++e) g[e] = (_Float16)x[e * HW + px];
    g[6] = (_Float16)sigma[px];
    g[7] = (_Float16)0.0f;
    *(half8*)(G + (size_t)px * 8) = g;
}

// Kernel B:
//   c1 = W1^T g   (MFMA1, K zero-padded 7->16)
//   h  = relu(c1 - q)          [C-layout == B-fragment layout: no shuffle]
//   c2 = W2^T h   (MFMA2);  prob = sigmoid(W3 . relu(c2+b2) + b3)
// 2-stage pipelined gather; row-base addressing (each wave-iter's 64 px are one
// contiguous row segment).  quad<2 guard is semantically required: MFMA1
// B-fragment rows k>=8 must stay zero (G has 8 channels).
__global__ __launch_bounds__(256) void instanseg_mlp(
    const _Float16* __restrict__ G,   // (1024*1024, 8)
    const float* __restrict__ c,      // (512, 6)
    const float* __restrict__ W1,     // (7, 16)
    const float* __restrict__ b1,     // (16)
    const float* __restrict__ W2,     // (16, 16)
    const float* __restrict__ b2,     // (16)
    const float* __restrict__ W3,     // (16, 1)
    const float* __restrict__ b3,     // (1)
    const int*   __restrict__ cent,   // (512, 2)
    float* __restrict__ out)
{
    const int cid  = blockIdx.y;
    const int lane = threadIdx.x & 63;
    const int wave = threadIdx.x >> 6;
    const int quad = lane >> 4;
    const int sub  = lane & 15;

    const int cy = min(max(cent[2 * cid], 64), 960);
    const int cx = min(max(cent[2 * cid + 1], 64), 960);
    const int cy0 = cy - 64, cx0 = cx - 64;

    // MFMA1 A-fragment: A[m=sub][k=4*quad+i] = W1[k][sub] (0 for k >= 7)
    half4 a1;
#pragma unroll
    for (int i = 0; i < 4; ++i) {
        const int k = 4 * quad + i;
        a1[i] = (k < 7) ? (_Float16)W1[k * 16 + sub] : (_Float16)0.0f;
    }

    // MFMA2 A-fragment + f32 layer-1 offset q and layer-2/3 constants
    half4 a2;
    float w3f[4], bb2[4], qf[4];
#pragma unroll
    for (int i = 0; i < 4; ++i) {
        const int k = 4 * quad + i;
        a2[i]  = (_Float16)W2[k * 16 + sub];
        w3f[i] = W3[k];
        bb2[i] = b2[k];
        float qv = -b1[k];
#pragma unroll
        for (int e = 0; e < 6; ++e)
            qv = fmaf(W1[e * 16 + k], c[cid * 6 + e], qv);
        qf[i] = qv;
    }
    const float b3v = b3[0];
    const floatx4 zero = {0.0f, 0.0f, 0.0f, 0.0f};

    const int wavestart = blockIdx.x * 2048 + wave * 512;

    // ---- 2-stage pipelined gather (quads 0-1 carry data; 2-3 stay zero) ----
    half4 v[4], vn[4];
#pragma unroll
    for (int ch = 0; ch < 4; ++ch) { v[ch] = (half4)(_Float16)0.0f; vn[ch] = (half4)(_Float16)0.0f; }
    {
        // wavestart % 512 == 0 -> one contiguous row segment per wave-iter
        const int base = (cy0 + (wavestart >> 7)) * 1024 + cx0 + sub;
        const _Float16* rowp = G + (size_t)base * 8 + quad * 4;
        if (quad < 2) {
#pragma unroll
            for (int ch = 0; ch < 4; ++ch)
                v[ch] = *(const half4*)(rowp + ch * 128);   // 16 px * 8 ch
        }
    }

    for (int it = 0; it < 8; ++it) {
        const int start = wavestart + it * 64;

        if (it < 7) {   // batch-issue next iteration's 4 fragment loads
            const int nstart = start + 64;
            const int base = (cy0 + (nstart >> 7)) * 1024 + cx0 + (nstart & 127) + sub;
            const _Float16* rowp = G + (size_t)base * 8 + quad * 4;
            if (quad < 2) {
#pragma unroll
                for (int ch = 0; ch < 4; ++ch)
                    vn[ch] = *(const half4*)(rowp + ch * 128);
            }
        }

        float logit[4];
#pragma unroll
        for (int ch = 0; ch < 4; ++ch) {
            // layer 1 on the matrix pipe
            floatx4 c1 = __builtin_amdgcn_mfma_f32_16x16x16f16(a1, v[ch], zero, 0, 0, 0);

            // h = relu(c1 - q), single fp16 rounding — C-layout == B-layout
            half4 h;
#pragma unroll
            for (int i = 0; i < 4; ++i)
                h[i] = (_Float16)fmaxf(c1[i] - qf[i], 0.0f);

            // layer 2 on the matrix pipe
            floatx4 c2 = __builtin_amdgcn_mfma_f32_16x16x16f16(a2, h, zero, 0, 0, 0);

            float part = 0.0f;
#pragma unroll
            for (int i = 0; i < 4; ++i)
                part = fmaf(w3f[i], fmaxf(c2[i] + bb2[i], 0.0f), part);
            part += __shfl_xor(part, 16, 64);
            part += __shfl_xor(part, 32, 64);
            logit[ch] = part;
        }

        const float l01 = (quad & 1) ? logit[1] : logit[0];
        const float l23 = (quad & 1) ? logit[3] : logit[2];
        const float lg  = (quad & 2) ? l23 : l01;
        const float prob = 1.0f / (1.0f + __expf(-(lg + b3v)));

        const int rowy = cy0 + (start >> 7);            // wave-uniform
        const int colx = cx0 + (start & 127) + lane;
        const int n    = cid * 16384 + start + lane;
        out[n]             = prob;
        out[PLANE + n]     = (float)cid;
        out[2 * PLANE + n] = (float)rowy;
        out[3 * PLANE + n] = (float)colx;

        if (it < 7) {
#pragma unroll
            for (int ch = 0; ch < 4; ++ch) v[ch] = vn[ch];
        }
    }
}

extern "C" void kernel_launch(void* const* d_in, const int* in_sizes, int n_in,
                              void* d_out, int out_size, void* d_ws, size_t ws_size,
                              hipStream_t stream) {
    const float* x     = (const float*)d_in[0];
    const float* sigma = (const float*)d_in[1];
    const float* c     = (const float*)d_in[2];
    const float* W1    = (const float*)d_in[3];
    const float* b1    = (const float*)d_in[4];
    const float* W2    = (const float*)d_in[5];
    const float* b2    = (const float*)d_in[6];
    const float* W3    = (const float*)d_in[7];
    const float* b3    = (const float*)d_in[8];
    const int*   cent  = (const int*)d_in[9];
    float* out = (float*)d_out;
    _Float16* G = (_Float16*)d_ws;   // 1024*1024*8 fp16 = 16 MB scratch

    precompute_G<<<dim3(HW / 256), dim3(256), 0, stream>>>(x, sigma, G);
    instanseg_mlp<<<dim3(8, 512), dim3(256), 0, stream>>>(
        G, c, W1, b1, W2, b2, W3, b3, cent, out);
}